// Round 9
// baseline (231.809 us; speedup 1.0000x reference)
//
#include <hip/hip_runtime.h>
#include <hip/hip_fp16.h>

typedef _Float16 f16;
typedef _Float16 f16x8 __attribute__((ext_vector_type(8)));
typedef _Float16 f16x4 __attribute__((ext_vector_type(4)));
typedef float f32x4 __attribute__((ext_vector_type(4)));

#define LN_EPS 1e-5f

// erf via Abramowitz-Stegun 7.1.26 (|eps| <= 1.5e-7)
__device__ __forceinline__ float erf_fast(float x) {
    const float ax = __builtin_fabsf(x);
    const float t = 1.0f / (1.0f + 0.3275911f * ax);
    const float y = t * (0.254829592f +
                    t * (-0.284496736f +
                    t * (1.421413741f +
                    t * (-1.453152027f +
                    t * 1.061405429f))));
    const float r = 1.0f - y * __expf(-ax * ax);
    return __builtin_copysignf(r, x);
}

__device__ __forceinline__ float gelu_exact(float v) {
    return 0.5f * v * (1.0f + erf_fast(v * 0.70710678118654752440f));
}

// async global -> LDS, 16B per lane; lds dest is wave-uniform base (+lane*16 by HW)
__device__ __forceinline__ void gload_lds16(const f16* g, f16* l) {
    __builtin_amdgcn_global_load_lds(
        (const __attribute__((address_space(1))) unsigned int*)(g),
        (__attribute__((address_space(3))) unsigned int*)(l),
        16, 0, 0);
}

// ---------------- LayerNorm(x) -> y_h (fp16), plus x -> x_h (fp16) ----------
__global__ __launch_bounds__(256)
void ln_cast_kernel(const float* __restrict__ x,
                    const float* __restrict__ gamma,
                    const float* __restrict__ beta,
                    f16* __restrict__ y_h,
                    f16* __restrict__ x_h) {
    const int row = blockIdx.x;
    const int t = threadIdx.x;
    const size_t base = (size_t)row * 1024;
    float4 v = ((const float4*)(x + base))[t];
    float s  = v.x + v.y + v.z + v.w;
    float s2 = v.x*v.x + v.y*v.y + v.z*v.z + v.w*v.w;
    #pragma unroll
    for (int off = 32; off > 0; off >>= 1) {
        s  += __shfl_down(s, off, 64);
        s2 += __shfl_down(s2, off, 64);
    }
    __shared__ float ls[4], ls2[4];
    const int wid = t >> 6;
    if ((t & 63) == 0) { ls[wid] = s; ls2[wid] = s2; }
    __syncthreads();
    if (t == 0) {
        ls[0]  = ls[0] + ls[1] + ls[2] + ls[3];
        ls2[0] = ls2[0] + ls2[1] + ls2[2] + ls2[3];
    }
    __syncthreads();
    const float mu   = ls[0] * (1.0f / 1024.0f);
    const float var  = ls2[0] * (1.0f / 1024.0f) - mu * mu;
    const float rstd = rsqrtf(var + LN_EPS);
    const float4 g  = ((const float4*)gamma)[t];
    const float4 bt = ((const float4*)beta)[t];
    f16x4 yo, xo;
    yo[0] = (f16)((v.x - mu) * rstd * g.x + bt.x);
    yo[1] = (f16)((v.y - mu) * rstd * g.y + bt.y);
    yo[2] = (f16)((v.z - mu) * rstd * g.z + bt.z);
    yo[3] = (f16)((v.w - mu) * rstd * g.w + bt.w);
    xo[0] = (f16)v.x; xo[1] = (f16)v.y; xo[2] = (f16)v.z; xo[3] = (f16)v.w;
    *(f16x4*)(y_h + base + t * 4) = yo;
    *(f16x4*)(x_h + base + t * 4) = xo;
}

// ---------------- final LayerNorm: pre (fp32) -> out (fp32) ----------------
__global__ __launch_bounds__(256)
void ln_final_kernel(const float* __restrict__ pre,
                     const float* __restrict__ gamma,
                     const float* __restrict__ beta,
                     float* __restrict__ out) {
    const int row = blockIdx.x;
    const int t = threadIdx.x;
    const size_t base = (size_t)row * 1024;
    float4 v = ((const float4*)(pre + base))[t];
    float s  = v.x + v.y + v.z + v.w;
    float s2 = v.x*v.x + v.y*v.y + v.z*v.z + v.w*v.w;
    #pragma unroll
    for (int off = 32; off > 0; off >>= 1) {
        s  += __shfl_down(s, off, 64);
        s2 += __shfl_down(s2, off, 64);
    }
    __shared__ float ls[4], ls2[4];
    const int wid = t >> 6;
    if ((t & 63) == 0) { ls[wid] = s; ls2[wid] = s2; }
    __syncthreads();
    if (t == 0) {
        ls[0]  = ls[0] + ls[1] + ls[2] + ls[3];
        ls2[0] = ls2[0] + ls2[1] + ls2[2] + ls2[3];
    }
    __syncthreads();
    const float mu   = ls[0] * (1.0f / 1024.0f);
    const float var  = ls2[0] * (1.0f / 1024.0f) - mu * mu;
    const float rstd = rsqrtf(var + LN_EPS);
    const float4 g  = ((const float4*)gamma)[t];
    const float4 bt = ((const float4*)beta)[t];
    float4 o;
    o.x = (v.x - mu) * rstd * g.x + bt.x;
    o.y = (v.y - mu) * rstd * g.y + bt.y;
    o.z = (v.z - mu) * rstd * g.z + bt.z;
    o.w = (v.w - mu) * rstd * g.w + bt.w;
    ((float4*)(out + base))[t] = o;
}

// ------------- transpose + cast fp32 [R,C] -> fp16 [C,R] -------------------
__global__ __launch_bounds__(256)
void transpose_cast_kernel(const float* __restrict__ src,
                           f16* __restrict__ dst, int R, int C) {
    __shared__ float tile[32][33];
    const int c0 = blockIdx.x * 32, r0 = blockIdx.y * 32;
    const int tx = threadIdx.x & 31, ty = threadIdx.x >> 5;
    #pragma unroll
    for (int i = 0; i < 4; ++i) {
        const int r = ty + i * 8;
        tile[r][tx] = src[(size_t)(r0 + r) * C + c0 + tx];
    }
    __syncthreads();
    #pragma unroll
    for (int i = 0; i < 4; ++i) {
        const int r = ty + i * 8;
        dst[(size_t)(c0 + r) * R + r0 + tx] = (f16)tile[tx][r];
    }
}

// ------------- batched transpose fp16 [R,C] -> fp16 [C,R] ------------------
__global__ __launch_bounds__(256)
void transpose_f16_kernel(const f16* __restrict__ src,
                          f16* __restrict__ dst, int R, int C) {
    __shared__ f16 tile[32][33];
    const size_t zb = (size_t)blockIdx.z * R * C;
    src += zb; dst += zb;
    const int c0 = blockIdx.x * 32, r0 = blockIdx.y * 32;
    const int tx = threadIdx.x & 31, ty = threadIdx.x >> 5;
    #pragma unroll
    for (int i = 0; i < 4; ++i) {
        const int r = ty + i * 8;
        tile[r][tx] = src[(size_t)(r0 + r) * C + c0 + tx];
    }
    __syncthreads();
    #pragma unroll
    for (int i = 0; i < 4; ++i) {
        const int r = ty + i * 8;
        dst[(size_t)(c0 + r) * R + r0 + tx] = tile[tx][r];
    }
}

// ====== 256x128 8-wave GEMM (NT), BK=32, ring-3 LDS, 2 blocks/CU ===========
// Wave grid 4(M) x 2(N), wave tile 64x64. LDS: A 3x16KB + B 3x8KB = 72KB
// -> 2 blocks/CU co-resident (16 waves, 4/SIMD): the two blocks' barrier
// convoys de-correlate, so one block's LDS phase overlaps the other's MFMA
// phase (m114 cross-wave pipe overlap; m97 ran 3 blocks/CU).
// Staging: 3 units/K-tile (A:2 x 128rows, B:1 x 128rows), each 512 lanes x
// 16B. Loop top: vmcnt(3) [tile kt landed (issued 2 iters ago); kt+1's 3 in
// flight] -> barrier -> stage kt+2 into slot(kt-1) -> 8 ds_read + 16 MFMA,
// compiler-scheduled. Swizzle: 16B slot s of row r holds k-slot s^(r&3);
// pre-swizzled global source, linear LDS dest.
// SWAP (EPI != 1): mfma(b,a) so acc reg index walks N -> vectorized stores.
// EPI: 0 = +bias, gelu, fp16 out [M][N]               (swapped)
//      1 = +bias, fp16 out transposed per batch [z][col][row%2048] (unswapped)
//      3 = fp32 out + xadd (batched via blockIdx.z)   (swapped)
template <int EPI>
__global__ __launch_bounds__(512, 4)
void gemm256x128_nt_kernel(const f16* __restrict__ A, const f16* __restrict__ Bt,
                           const float* __restrict__ bias,
                           const float* __restrict__ xadd,
                           f16* __restrict__ outH, float* __restrict__ outF,
                           int M, int N, int K,
                           long long batchA, long long batchB, long long batchC) {
    __shared__ __attribute__((aligned(16))) f16 sA[3][256 * 32];
    __shared__ __attribute__((aligned(16))) f16 sB[3][128 * 32];

    const int z = blockIdx.z;
    A  += (size_t)z * batchA;
    Bt += (size_t)z * batchB;

    const int m0 = blockIdx.x * 256;
    const int n0 = blockIdx.y * 128;
    const int t = threadIdx.x;
    const int l = t & 63;
    const int wid = t >> 6;
    const int wr = wid >> 1;      // 0-3 (M)
    const int wc = wid & 1;       // 0-1 (N)
    const int rl = l & 15;
    const int g  = l >> 4;        // 0-3
    const int nk = K >> 5;

    // staging: unit = 512 lanes x 16B = 128 rows x 32 f16. thread t covers
    // row t>>2 (0..127), slot t&3; source k-slot = slot ^ (row&3).
    const int rowS = t >> 2;                       // 0..127
    const int kbS  = ((t & 3) ^ (rowS & 3)) * 8;
    const f16* pA = A  + (size_t)(m0 + rowS) * K + kbS;
    const f16* pB = Bt + (size_t)(n0 + rowS) * K + kbS;
    const int ldsS = wid * 512;   // wave-uniform base within unit (HW +lane*16B)

    const int rA = wr * 64 + rl;
    const int rB = wc * 64 + rl;
    const int swk = (g ^ (rl & 3)) * 8;

    f32x4 acc[4][4] = {};

    auto mf = [&](f32x4 c, f16x8 af, f16x8 bf) {
        if constexpr (EPI != 1)
            return __builtin_amdgcn_mfma_f32_16x16x32_f16(bf, af, c, 0, 0, 0);
        else
            return __builtin_amdgcn_mfma_f32_16x16x32_f16(af, bf, c, 0, 0, 0);
    };

    auto stgA = [&](f16* dst, int u, int kc) {   // u = 0..1 (128-row halves)
        gload_lds16(pA + (size_t)u * 128 * K + kc * 32, dst + u * 4096 + ldsS);
    };
    auto stgB = [&](f16* dst, int kc) {
        gload_lds16(pB + kc * 32, dst + ldsS);
    };

    // prologue: tiles 0 and 1 (6 units outstanding)
    const int t1 = (nk > 1) ? 1 : 0;
    stgA(sA[0], 0, 0); stgA(sA[0], 1, 0); stgB(sB[0], 0);
    stgA(sA[1], 0, t1); stgA(sA[1], 1, t1); stgB(sB[1], t1);

    f16 *curA = sA[0], *nxtA = sA[1], *farA = sA[2];
    f16 *curB = sB[0], *nxtB = sB[1], *farB = sB[2];

    f16x8 a[4], b[4];

    for (int kt = 0; kt < nk; ++kt) {
        // tile kt landed for this wave; kt+1's 3 units stay in flight
        asm volatile("s_waitcnt vmcnt(3)" ::: "memory");
        __builtin_amdgcn_s_barrier();
        asm volatile("" ::: "memory");   // compiler fence: no hoisting above barrier

        const int kt2 = (kt + 2 < nk) ? kt + 2 : nk - 1;

        // stage kt+2 into slot(kt-1); reads of that slot finished pre-barrier
        stgA(farA, 0, kt2);
        stgA(farA, 1, kt2);
        stgB(farB, kt2);

        // flat body: reads + MFMAs, compiler-scheduled (counted lgkmcnt)
        #pragma unroll
        for (int fm = 0; fm < 4; ++fm)
            a[fm] = *(const f16x8*)(curA + (rA + fm * 16) * 32 + swk);
        #pragma unroll
        for (int fn = 0; fn < 4; ++fn)
            b[fn] = *(const f16x8*)(curB + (rB + fn * 16) * 32 + swk);

        #pragma unroll
        for (int fm = 0; fm < 4; ++fm)
            #pragma unroll
            for (int fn = 0; fn < 4; ++fn)
                acc[fm][fn] = mf(acc[fm][fn], a[fm], b[fn]);

        // rotate ring
        f16* tp;
        tp = curA; curA = nxtA; nxtA = farA; farA = tp;
        tp = curB; curB = nxtB; nxtB = farB; farB = tp;
    }
    asm volatile("s_waitcnt vmcnt(0)" ::: "memory");

    // ---------------- epilogue ----------------
    if (EPI == 1) {
        // unswapped: reg r walks M (=T) -> f16x4 along T in transposed out
        #pragma unroll
        for (int fm = 0; fm < 4; ++fm) {
            #pragma unroll
            for (int fn = 0; fn < 4; ++fn) {
                const int col = n0 + wc * 64 + fn * 16 + rl;
                const int row0 = m0 + wr * 64 + fm * 16 + g * 4;
                const int zz = row0 >> 11;
                const int rr = row0 & 2047;
                const float bv = bias[col];
                f16x4 o;
                #pragma unroll
                for (int r = 0; r < 4; ++r) o[r] = (f16)(acc[fm][fn][r] + bv);
                *(f16x4*)(outH + ((size_t)zz * N + col) * 2048 + rr) = o;
            }
        }
    } else {
        // swapped: lane rl walks M-row, reg r walks N-col -> vector stores
        const float* xaddz = xadd;
        float* outFz = outF;
        if (EPI == 3) {
            outFz += (size_t)z * batchC;
            xaddz += (size_t)z * batchC;
        }
        #pragma unroll
        for (int fm = 0; fm < 4; ++fm) {
            const int row = m0 + wr * 64 + fm * 16 + rl;
            #pragma unroll
            for (int fn = 0; fn < 4; ++fn) {
                const int colb = n0 + wc * 64 + fn * 16 + g * 4;
                if (EPI == 0) {
                    const float4 bv = *(const float4*)&bias[colb];
                    f16x4 o;
                    o[0] = (f16)gelu_exact(acc[fm][fn][0] + bv.x);
                    o[1] = (f16)gelu_exact(acc[fm][fn][1] + bv.y);
                    o[2] = (f16)gelu_exact(acc[fm][fn][2] + bv.z);
                    o[3] = (f16)gelu_exact(acc[fm][fn][3] + bv.w);
                    *(f16x4*)(outH + (size_t)row * N + colb) = o;
                } else {
                    const size_t idx = (size_t)row * N + colb;
                    const float4 xa = *(const float4*)&xaddz[idx];
                    float4 o;
                    o.x = acc[fm][fn][0] + xa.x;
                    o.y = acc[fm][fn][1] + xa.y;
                    o.z = acc[fm][fn][2] + xa.z;
                    o.w = acc[fm][fn][3] + xa.w;
                    *(float4*)(outFz + idx) = o;
                }
            }
        }
    }
}

// ---------------- GEMM (NT) 128^2 ring-3, swapped epilogue (g2) ------------
__global__ __launch_bounds__(256, 3)
void gemm_nt_kernel(const f16* __restrict__ A, const f16* __restrict__ Bt,
                    f16* __restrict__ outH,
                    int M, int N, int K,
                    long long batchA, long long batchB, long long batchC) {
    __shared__ __attribute__((aligned(16))) f16 sA[3][128 * 32];
    __shared__ __attribute__((aligned(16))) f16 sB[3][128 * 32];

    const int z = blockIdx.z;
    A  += (size_t)z * batchA;
    Bt += (size_t)z * batchB;

    const int m0 = blockIdx.x * 128;
    const int n0 = blockIdx.y * 128;
    const int t = threadIdx.x;
    const int l = t & 63;
    const int wid = t >> 6;
    const int wm = (wid >> 1) * 64;
    const int wn = (wid & 1) * 64;

    f32x4 acc[4][4] = {};

    const int rl = l & 15;
    const int nk = K >> 5;

    const int row0 = t >> 2;
    const int kb = ((t & 3) ^ (row0 & 3)) * 8;
    const f16* Ag0 = A  + (size_t)(m0 + row0) * K + kb;
    const f16* Ag1 = A  + (size_t)(m0 + row0 + 64) * K + kb;
    const f16* Bg0 = Bt + (size_t)(n0 + row0) * K + kb;
    const f16* Bg1 = Bt + (size_t)(n0 + row0 + 64) * K + kb;
    const int lo0 = wid * 512;
    const int lo1 = 2048 + wid * 512;

    const int swk = (((l >> 4) ^ (rl & 3))) * 8;

    gload_lds16(Ag0,      sA[0] + lo0);
    gload_lds16(Ag1,      sA[0] + lo1);
    gload_lds16(Bg0,      sB[0] + lo0);
    gload_lds16(Bg1,      sB[0] + lo1);
    gload_lds16(Ag0 + 32, sA[1] + lo0);
    gload_lds16(Ag1 + 32, sA[1] + lo1);
    gload_lds16(Bg0 + 32, sB[1] + lo0);
    gload_lds16(Bg1 + 32, sB[1] + lo1);

    f16 *curA = sA[0], *nxtA = sA[1], *farA = sA[2];
    f16 *curB = sB[0], *nxtB = sB[1], *farB = sB[2];

    for (int kt = 0; kt < nk; ++kt) {
        asm volatile("s_waitcnt vmcnt(4)" ::: "memory");
        __builtin_amdgcn_s_barrier();
        asm volatile("" ::: "memory");

        const int ktn = (kt + 2 < nk) ? kt + 2 : nk - 1;
        const int kof = ktn * 32;
        gload_lds16(Ag0 + kof, farA + lo0);
        gload_lds16(Ag1 + kof, farA + lo1);
        gload_lds16(Bg0 + kof, farB + lo0);
        gload_lds16(Bg1 + kof, farB + lo1);

        f16x8 a[4], b[4];
        #pragma unroll
        for (int f = 0; f < 4; ++f) {
            a[f] = *(const f16x8*)&curA[(wm + f * 16 + rl) * 32 + swk];
            b[f] = *(const f16x8*)&curB[(wn + f * 16 + rl) * 32 + swk];
        }
        // swapped: acc reg walks N
        #pragma unroll
        for (int fm = 0; fm < 4; ++fm)
            #pragma unroll
            for (int fn = 0; fn < 4; ++fn)
                acc[fm][fn] = __builtin_amdgcn_mfma_f32_16x16x32_f16(
                    b[fn], a[fm], acc[fm][fn], 0, 0, 0);

        f16* tA = curA; curA = nxtA; nxtA = farA; farA = tA;
        f16* tB = curB; curB = nxtB; nxtB = farB; farB = tB;
    }
    asm volatile("s_waitcnt vmcnt(0)" ::: "memory");

    const int rh = l >> 4;
    f16* outHz = outH + (size_t)z * batchC;
    #pragma unroll
    for (int fm = 0; fm < 4; ++fm) {
        const int row = m0 + wm + fm * 16 + rl;
        #pragma unroll
        for (int fn = 0; fn < 4; ++fn) {
            const int colb = n0 + wn + fn * 16 + rh * 4;
            f16x4 o;
            #pragma unroll
            for (int r = 0; r < 4; ++r) o[r] = (f16)acc[fm][fn][r];
            *(f16x4*)(outHz + (size_t)row * N + colb) = o;
        }
    }
}

extern "C" void kernel_launch(void* const* d_in, const int* in_sizes, int n_in,
                              void* d_out, int out_size, void* d_ws, size_t ws_size,
                              hipStream_t stream) {
    const float* x     = (const float*)d_in[0];
    const float* gamma = (const float*)d_in[1];
    const float* beta  = (const float*)d_in[2];
    const float* w1    = (const float*)d_in[3];
    const float* b1    = (const float*)d_in[4];
    const float* w2    = (const float*)d_in[5];
    const float* b2    = (const float*)d_in[6];
    float* out = (float*)d_out;

    const int BS = 4, T = 2048, DIM = 1024, HID = 2048;
    const int M = BS * T;  // 8192
    const long long MB = 1024 * 1024;

    // workspace layout (112 MiB total)
    char* ws = (char*)d_ws;
    f16*   x_h  = (f16*)(ws + 0 * MB);    // 16 MiB [M][DIM]
    f16*   y_h  = (f16*)(ws + 16 * MB);   // 16 MiB [M][DIM]
    f16*   h    = (f16*)(ws + 32 * MB);   // 32 MiB [M][HID]
    float* pre  = (float*)h;              // alias: h dead after GEMM2
    f16*   y2t  = (f16*)(ws + 64 * MB);   // 16 MiB [BS][DIM][T]
    f16*   x_t  = (f16*)(ws + 80 * MB);   // 16 MiB [BS][DIM][T]
    f16*   G    = (f16*)(ws + 96 * MB);   // 8 MiB  [BS][DIM][DIM]
    f16*   w1t  = (f16*)(ws + 104 * MB);  // 4 MiB  [HID][DIM]
    f16*   w2t  = (f16*)(ws + 108 * MB);  // 4 MiB  [DIM][HID]

    // 1) first LN + fp16 casts
    ln_cast_kernel<<<M, 256, 0, stream>>>(x, gamma, beta, y_h, x_h);

    // 2) weight transposes to fp16 [N][K]
    transpose_cast_kernel<<<dim3(HID / 32, DIM / 32), 256, 0, stream>>>(w1, w1t, DIM, HID);
    transpose_cast_kernel<<<dim3(DIM / 32, HID / 32), 256, 0, stream>>>(w2, w2t, HID, DIM);

    // 3) h = gelu(y @ w1 + b1)   [M][HID]  -- 256x128 BK32 ring-3, swapped epi
    gemm256x128_nt_kernel<0><<<dim3(M / 256, HID / 128, 1), 512, 0, stream>>>(
        y_h, w1t, b1, nullptr, h, nullptr, M, HID, DIM, 0, 0, 0);

    // 4) y2t[z][f][t] = (h @ w2 + b2)[z*T+t][f]  -- 256x128 BK32, transposed epi
    gemm256x128_nt_kernel<1><<<dim3(M / 256, DIM / 128, 1), 512, 0, stream>>>(
        h, w2t, b2, nullptr, y2t, nullptr, M, DIM, HID, 0, 0, 0);

    // 5) x_t[z][f][t] = x_h[z*T+t][f]
    transpose_f16_kernel<<<dim3(DIM / 32, T / 32, BS), 256, 0, stream>>>(x_h, x_t, T, DIM);

    // 6) G'[z][f2][f1] = sum_t y2t[z][f2][t] * x_t[z][f1][t]  -- 128^2 ring-3
    gemm_nt_kernel<<<dim3(DIM / 128, DIM / 128, BS), 256, 0, stream>>>(
        y2t, x_t, G, DIM, DIM, T,
        (long long)DIM * T, (long long)DIM * T, (long long)DIM * DIM);

    // 7) pre[z][t][f] = sum_k x_h[z][t][k] * G'[z][f][k] + x  -- 256x128 BK32
    gemm256x128_nt_kernel<3><<<dim3(T / 256, DIM / 128, BS), 512, 0, stream>>>(
        x_h, G, nullptr, x, nullptr, pre, T, DIM, DIM,
        (long long)T * DIM, (long long)DIM * DIM, (long long)T * DIM);

    // 8) final LN
    ln_final_kernel<<<M, 256, 0, stream>>>(pre, gamma, beta, out);
}

// Round 10
// 197.664 us; speedup vs baseline: 1.1727x; 1.1727x over previous
//
#include <hip/hip_runtime.h>
#include <hip/hip_fp16.h>

typedef _Float16 f16;
typedef _Float16 f16x8 __attribute__((ext_vector_type(8)));
typedef _Float16 f16x4 __attribute__((ext_vector_type(4)));
typedef float f32x4 __attribute__((ext_vector_type(4)));

#define LN_EPS 1e-5f

// erf via Abramowitz-Stegun 7.1.26 (|eps| <= 1.5e-7)
__device__ __forceinline__ float erf_fast(float x) {
    const float ax = __builtin_fabsf(x);
    const float t = 1.0f / (1.0f + 0.3275911f * ax);
    const float y = t * (0.254829592f +
                    t * (-0.284496736f +
                    t * (1.421413741f +
                    t * (-1.453152027f +
                    t * 1.061405429f))));
    const float r = 1.0f - y * __expf(-ax * ax);
    return __builtin_copysignf(r, x);
}

__device__ __forceinline__ float gelu_exact(float v) {
    return 0.5f * v * (1.0f + erf_fast(v * 0.70710678118654752440f));
}

// async global -> LDS, 16B per lane; lds dest is wave-uniform base (+lane*16 by HW)
__device__ __forceinline__ void gload_lds16(const f16* g, f16* l) {
    __builtin_amdgcn_global_load_lds(
        (const __attribute__((address_space(1))) unsigned int*)(g),
        (__attribute__((address_space(3))) unsigned int*)(l),
        16, 0, 0);
}

// ---------------- LayerNorm(x) -> y_h (fp16), plus x -> x_h (fp16) ----------
__global__ __launch_bounds__(256)
void ln_cast_kernel(const float* __restrict__ x,
                    const float* __restrict__ gamma,
                    const float* __restrict__ beta,
                    f16* __restrict__ y_h,
                    f16* __restrict__ x_h) {
    const int row = blockIdx.x;
    const int t = threadIdx.x;
    const size_t base = (size_t)row * 1024;
    float4 v = ((const float4*)(x + base))[t];
    float s  = v.x + v.y + v.z + v.w;
    float s2 = v.x*v.x + v.y*v.y + v.z*v.z + v.w*v.w;
    #pragma unroll
    for (int off = 32; off > 0; off >>= 1) {
        s  += __shfl_down(s, off, 64);
        s2 += __shfl_down(s2, off, 64);
    }
    __shared__ float ls[4], ls2[4];
    const int wid = t >> 6;
    if ((t & 63) == 0) { ls[wid] = s; ls2[wid] = s2; }
    __syncthreads();
    if (t == 0) {
        ls[0]  = ls[0] + ls[1] + ls[2] + ls[3];
        ls2[0] = ls2[0] + ls2[1] + ls2[2] + ls2[3];
    }
    __syncthreads();
    const float mu   = ls[0] * (1.0f / 1024.0f);
    const float var  = ls2[0] * (1.0f / 1024.0f) - mu * mu;
    const float rstd = rsqrtf(var + LN_EPS);
    const float4 g  = ((const float4*)gamma)[t];
    const float4 bt = ((const float4*)beta)[t];
    f16x4 yo, xo;
    yo[0] = (f16)((v.x - mu) * rstd * g.x + bt.x);
    yo[1] = (f16)((v.y - mu) * rstd * g.y + bt.y);
    yo[2] = (f16)((v.z - mu) * rstd * g.z + bt.z);
    yo[3] = (f16)((v.w - mu) * rstd * g.w + bt.w);
    xo[0] = (f16)v.x; xo[1] = (f16)v.y; xo[2] = (f16)v.z; xo[3] = (f16)v.w;
    *(f16x4*)(y_h + base + t * 4) = yo;
    *(f16x4*)(x_h + base + t * 4) = xo;
}

// ---------------- final LayerNorm: pre (f16) -> out (fp32) ----------------
__global__ __launch_bounds__(256)
void ln_final_kernel(const f16* __restrict__ pre,
                     const float* __restrict__ gamma,
                     const float* __restrict__ beta,
                     float* __restrict__ out) {
    const int row = blockIdx.x;
    const int t = threadIdx.x;
    const size_t base = (size_t)row * 1024;
    const f16x4 vh = *(const f16x4*)(pre + base + t * 4);
    float4 v;
    v.x = (float)vh[0]; v.y = (float)vh[1]; v.z = (float)vh[2]; v.w = (float)vh[3];
    float s  = v.x + v.y + v.z + v.w;
    float s2 = v.x*v.x + v.y*v.y + v.z*v.z + v.w*v.w;
    #pragma unroll
    for (int off = 32; off > 0; off >>= 1) {
        s  += __shfl_down(s, off, 64);
        s2 += __shfl_down(s2, off, 64);
    }
    __shared__ float ls[4], ls2[4];
    const int wid = t >> 6;
    if ((t & 63) == 0) { ls[wid] = s; ls2[wid] = s2; }
    __syncthreads();
    if (t == 0) {
        ls[0]  = ls[0] + ls[1] + ls[2] + ls[3];
        ls2[0] = ls2[0] + ls2[1] + ls2[2] + ls2[3];
    }
    __syncthreads();
    const float mu   = ls[0] * (1.0f / 1024.0f);
    const float var  = ls2[0] * (1.0f / 1024.0f) - mu * mu;
    const float rstd = rsqrtf(var + LN_EPS);
    const float4 g  = ((const float4*)gamma)[t];
    const float4 bt = ((const float4*)beta)[t];
    float4 o;
    o.x = (v.x - mu) * rstd * g.x + bt.x;
    o.y = (v.y - mu) * rstd * g.y + bt.y;
    o.z = (v.z - mu) * rstd * g.z + bt.z;
    o.w = (v.w - mu) * rstd * g.w + bt.w;
    ((float4*)(out + base))[t] = o;
}

// ------------- transpose + cast fp32 [R,C] -> fp16 [C,R] -------------------
__global__ __launch_bounds__(256)
void transpose_cast_kernel(const float* __restrict__ src,
                           f16* __restrict__ dst, int R, int C) {
    __shared__ float tile[32][33];
    const int c0 = blockIdx.x * 32, r0 = blockIdx.y * 32;
    const int tx = threadIdx.x & 31, ty = threadIdx.x >> 5;
    #pragma unroll
    for (int i = 0; i < 4; ++i) {
        const int r = ty + i * 8;
        tile[r][tx] = src[(size_t)(r0 + r) * C + c0 + tx];
    }
    __syncthreads();
    #pragma unroll
    for (int i = 0; i < 4; ++i) {
        const int r = ty + i * 8;
        dst[(size_t)(c0 + r) * R + r0 + tx] = (f16)tile[tx][r];
    }
}

// ------------- batched transpose fp16 [R,C] -> fp16 [C,R] ------------------
__global__ __launch_bounds__(256)
void transpose_f16_kernel(const f16* __restrict__ src,
                          f16* __restrict__ dst, int R, int C) {
    __shared__ f16 tile[32][33];
    const size_t zb = (size_t)blockIdx.z * R * C;
    src += zb; dst += zb;
    const int c0 = blockIdx.x * 32, r0 = blockIdx.y * 32;
    const int tx = threadIdx.x & 31, ty = threadIdx.x >> 5;
    #pragma unroll
    for (int i = 0; i < 4; ++i) {
        const int r = ty + i * 8;
        tile[r][tx] = src[(size_t)(r0 + r) * C + c0 + tx];
    }
    __syncthreads();
    #pragma unroll
    for (int i = 0; i < 4; ++i) {
        const int r = ty + i * 8;
        dst[(size_t)(c0 + r) * R + r0 + tx] = tile[tx][r];
    }
}

// ====== 256x128 8-wave GEMM (NT), BK=64, ring-3 LDS, 4 phases/K-tile =======
// (round-7 core: best measured, 49.4 us on g0)
// Wave grid 4(M) x 2(N), wave tile 64x64. LDS: A 3x32KB + B 3x16KB = 144KB.
// Per tile: vmcnt(6) -> barrier; phases stage kt+2 into slot(kt-1) and
// interleave ds_read/MFMA with lgkmcnt(0)+setprio per phase.
// Swizzle: 16B slot s of row r holds k-slot s^(r&7); pre-swizzled global src.
// EPI: 0 = +bias, gelu, f16 out [M][N]                 (swapped mfma(b,a))
//      1 = +bias, f16 out transposed per batch via LDS  (unswapped)
//      3 = + xadd(fp32), f16 out [M][N] batched         (swapped)
template <int EPI>
__global__ __launch_bounds__(512, 2)
void gemm256x128_nt_kernel(const f16* __restrict__ A, const f16* __restrict__ Bt,
                           const float* __restrict__ bias,
                           const float* __restrict__ xadd,
                           f16* __restrict__ outH,
                           int M, int N, int K,
                           long long batchA, long long batchB, long long batchC) {
    __shared__ __attribute__((aligned(16))) f16 sA[3][256 * 64];
    __shared__ __attribute__((aligned(16))) f16 sB[3][128 * 64];

    const int z = blockIdx.z;
    A  += (size_t)z * batchA;
    Bt += (size_t)z * batchB;

    const int m0 = blockIdx.x * 256;
    const int n0 = blockIdx.y * 128;
    const int t = threadIdx.x;
    const int l = t & 63;
    const int wid = t >> 6;
    const int wr = wid >> 1;      // 0-3 (M)
    const int wc = wid & 1;       // 0-1 (N)
    const int rl = l & 15;
    const int g  = l >> 4;        // 0-3
    const int nk = K >> 6;

    const int rowS = t >> 3;                       // 0..63
    const int kbS  = ((t & 7) ^ (rowS & 7)) * 8;
    const f16* pA = A  + (size_t)(m0 + rowS) * K + kbS;
    const f16* pB = Bt + (size_t)(n0 + rowS) * K + kbS;
    const int ldsS = wid * 512;

    const int rA = wr * 64 + rl;
    const int rB = wc * 64 + rl;
    const int swk0 = ((g)     ^ (rl & 7)) * 8;
    const int swk1 = ((4 + g) ^ (rl & 7)) * 8;

    f32x4 acc[4][4] = {};

    auto mf = [&](f32x4 c, f16x8 af, f16x8 bf) {
        if constexpr (EPI != 1)
            return __builtin_amdgcn_mfma_f32_16x16x32_f16(bf, af, c, 0, 0, 0);
        else
            return __builtin_amdgcn_mfma_f32_16x16x32_f16(af, bf, c, 0, 0, 0);
    };

    auto stgA = [&](f16* dst, int u, int kc) {   // u = 0..3
        gload_lds16(pA + (size_t)u * 64 * K + kc * 64, dst + u * 4096 + ldsS);
    };
    auto stgB = [&](f16* dst, int u, int kc) {   // u = 0..1
        gload_lds16(pB + (size_t)u * 64 * K + kc * 64, dst + u * 4096 + ldsS);
    };

    // prologue: tiles 0 and 1 (12 units outstanding)
    const int t1 = (nk > 1) ? 1 : 0;
    #pragma unroll
    for (int u = 0; u < 4; ++u) stgA(sA[0], u, 0);
    #pragma unroll
    for (int u = 0; u < 2; ++u) stgB(sB[0], u, 0);
    #pragma unroll
    for (int u = 0; u < 4; ++u) stgA(sA[1], u, t1);
    #pragma unroll
    for (int u = 0; u < 2; ++u) stgB(sB[1], u, t1);

    f16 *curA = sA[0], *nxtA = sA[1], *farA = sA[2];
    f16 *curB = sB[0], *nxtB = sB[1], *farB = sB[2];

    f16x8 a[4][2], b[4][2];

    for (int kt = 0; kt < nk; ++kt) {
        asm volatile("s_waitcnt vmcnt(6)" ::: "memory");
        __builtin_amdgcn_s_barrier();

        const int kt2 = (kt + 2 < nk) ? kt + 2 : nk - 1;

        // P0: rd a01+b01, stg A-units 0,1; MFMA fm01 x fn01
        #pragma unroll
        for (int fm = 0; fm < 2; ++fm) {
            a[fm][0] = *(const f16x8*)(curA + (rA + fm * 16) * 64 + swk0);
            a[fm][1] = *(const f16x8*)(curA + (rA + fm * 16) * 64 + swk1);
        }
        #pragma unroll
        for (int fn = 0; fn < 2; ++fn) {
            b[fn][0] = *(const f16x8*)(curB + (rB + fn * 16) * 64 + swk0);
            b[fn][1] = *(const f16x8*)(curB + (rB + fn * 16) * 64 + swk1);
        }
        stgA(farA, 0, kt2);
        stgA(farA, 1, kt2);
        asm volatile("s_waitcnt lgkmcnt(0)" ::: "memory");
        __builtin_amdgcn_sched_barrier(0);
        __builtin_amdgcn_s_setprio(1);
        #pragma unroll
        for (int fm = 0; fm < 2; ++fm)
            #pragma unroll
            for (int fn = 0; fn < 2; ++fn) {
                acc[fm][fn] = mf(acc[fm][fn], a[fm][0], b[fn][0]);
                acc[fm][fn] = mf(acc[fm][fn], a[fm][1], b[fn][1]);
            }
        __builtin_amdgcn_s_setprio(0);

        // P1: rd b23, stg A-units 2,3; MFMA fm01 x fn23
        #pragma unroll
        for (int fn = 2; fn < 4; ++fn) {
            b[fn][0] = *(const f16x8*)(curB + (rB + fn * 16) * 64 + swk0);
            b[fn][1] = *(const f16x8*)(curB + (rB + fn * 16) * 64 + swk1);
        }
        stgA(farA, 2, kt2);
        stgA(farA, 3, kt2);
        asm volatile("s_waitcnt lgkmcnt(0)" ::: "memory");
        __builtin_amdgcn_sched_barrier(0);
        __builtin_amdgcn_s_setprio(1);
        #pragma unroll
        for (int fm = 0; fm < 2; ++fm)
            #pragma unroll
            for (int fn = 2; fn < 4; ++fn) {
                acc[fm][fn] = mf(acc[fm][fn], a[fm][0], b[fn][0]);
                acc[fm][fn] = mf(acc[fm][fn], a[fm][1], b[fn][1]);
            }
        __builtin_amdgcn_s_setprio(0);

        // P2: rd a23, stg B-units 0,1; MFMA fm23 x fn23
        #pragma unroll
        for (int fm = 2; fm < 4; ++fm) {
            a[fm][0] = *(const f16x8*)(curA + (rA + fm * 16) * 64 + swk0);
            a[fm][1] = *(const f16x8*)(curA + (rA + fm * 16) * 64 + swk1);
        }
        stgB(farB, 0, kt2);
        stgB(farB, 1, kt2);
        asm volatile("s_waitcnt lgkmcnt(0)" ::: "memory");
        __builtin_amdgcn_sched_barrier(0);
        __builtin_amdgcn_s_setprio(1);
        #pragma unroll
        for (int fm = 2; fm < 4; ++fm)
            #pragma unroll
            for (int fn = 2; fn < 4; ++fn) {
                acc[fm][fn] = mf(acc[fm][fn], a[fm][0], b[fn][0]);
                acc[fm][fn] = mf(acc[fm][fn], a[fm][1], b[fn][1]);
            }
        __builtin_amdgcn_s_setprio(0);

        // P3: MFMA fm23 x fn01 (operands in regs)
        __builtin_amdgcn_s_setprio(1);
        #pragma unroll
        for (int fm = 2; fm < 4; ++fm)
            #pragma unroll
            for (int fn = 0; fn < 2; ++fn) {
                acc[fm][fn] = mf(acc[fm][fn], a[fm][0], b[fn][0]);
                acc[fm][fn] = mf(acc[fm][fn], a[fm][1], b[fn][1]);
            }
        __builtin_amdgcn_s_setprio(0);

        f16* tp;
        tp = curA; curA = nxtA; nxtA = farA; farA = tp;
        tp = curB; curB = nxtB; nxtB = farB; farB = tp;
    }

    // ---------------- epilogue ----------------
    if (EPI == 1) {
        // LDS-transpose epilogue: coalesced 512B-run writes to y2t.
        // lds_t[128][264] f16 (67.6KB, reuses sA; stride 264 -> 16B-aligned
        // rows, conflict-free b128 reads). __syncthreads drains vm+lgkm and
        // fences all waves' K-loop LDS reads before overwrite.
        __syncthreads();
        f16* lds_t = (f16*)sA;
        #pragma unroll
        for (int fm = 0; fm < 4; ++fm) {
            const int rowb = wr * 64 + fm * 16 + g * 4;
            #pragma unroll
            for (int fn = 0; fn < 4; ++fn) {
                const int cl = wc * 64 + fn * 16 + rl;
                const float bv = bias[n0 + cl];
                f16x4 o;
                #pragma unroll
                for (int r = 0; r < 4; ++r) o[r] = (f16)(acc[fm][fn][r] + bv);
                *(f16x4*)&lds_t[cl * 264 + rowb] = o;
            }
        }
        __syncthreads();
        const int lh = l & 31, ch = l >> 5;
        #pragma unroll
        for (int it = 0; it < 8; ++it) {
            const int c = it * 16 + wid * 2 + ch;
            const f16x8 vv = *(const f16x8*)&lds_t[c * 264 + lh * 8];
            const int rowg = m0 + lh * 8;
            const int zz = rowg >> 11, rr = rowg & 2047;
            *(f16x8*)(outH + ((size_t)zz * N + (n0 + c)) * 2048 + rr) = vv;
        }
    } else {
        asm volatile("s_waitcnt vmcnt(0)" ::: "memory");
        // swapped: lane rl walks M-row, reg r walks N-col -> vector stores
        const float* xaddz = xadd;
        f16* outHz = outH;
        if (EPI == 3) {
            outHz += (size_t)z * batchC;
            xaddz += (size_t)z * batchC;
        }
        #pragma unroll
        for (int fm = 0; fm < 4; ++fm) {
            const int row = m0 + wr * 64 + fm * 16 + rl;
            #pragma unroll
            for (int fn = 0; fn < 4; ++fn) {
                const int colb = n0 + wc * 64 + fn * 16 + g * 4;
                if (EPI == 0) {
                    const float4 bv = *(const float4*)&bias[colb];
                    f16x4 o;
                    o[0] = (f16)gelu_exact(acc[fm][fn][0] + bv.x);
                    o[1] = (f16)gelu_exact(acc[fm][fn][1] + bv.y);
                    o[2] = (f16)gelu_exact(acc[fm][fn][2] + bv.z);
                    o[3] = (f16)gelu_exact(acc[fm][fn][3] + bv.w);
                    *(f16x4*)(outH + (size_t)row * N + colb) = o;
                } else {
                    const size_t idx = (size_t)row * N + colb;
                    const float4 xa = *(const float4*)&xaddz[idx];
                    f16x4 o;
                    o[0] = (f16)(acc[fm][fn][0] + xa.x);
                    o[1] = (f16)(acc[fm][fn][1] + xa.y);
                    o[2] = (f16)(acc[fm][fn][2] + xa.z);
                    o[3] = (f16)(acc[fm][fn][3] + xa.w);
                    *(f16x4*)(outHz + idx) = o;
                }
            }
        }
    }
}

// ---------------- GEMM (NT) 128^2 ring-3, swapped epilogue (g2) ------------
__global__ __launch_bounds__(256, 3)
void gemm_nt_kernel(const f16* __restrict__ A, const f16* __restrict__ Bt,
                    f16* __restrict__ outH,
                    int M, int N, int K,
                    long long batchA, long long batchB, long long batchC) {
    __shared__ __attribute__((aligned(16))) f16 sA[3][128 * 32];
    __shared__ __attribute__((aligned(16))) f16 sB[3][128 * 32];

    const int z = blockIdx.z;
    A  += (size_t)z * batchA;
    Bt += (size_t)z * batchB;

    const int m0 = blockIdx.x * 128;
    const int n0 = blockIdx.y * 128;
    const int t = threadIdx.x;
    const int l = t & 63;
    const int wid = t >> 6;
    const int wm = (wid >> 1) * 64;
    const int wn = (wid & 1) * 64;

    f32x4 acc[4][4] = {};

    const int rl = l & 15;
    const int nk = K >> 5;

    const int row0 = t >> 2;
    const int kb = ((t & 3) ^ (row0 & 3)) * 8;
    const f16* Ag0 = A  + (size_t)(m0 + row0) * K + kb;
    const f16* Ag1 = A  + (size_t)(m0 + row0 + 64) * K + kb;
    const f16* Bg0 = Bt + (size_t)(n0 + row0) * K + kb;
    const f16* Bg1 = Bt + (size_t)(n0 + row0 + 64) * K + kb;
    const int lo0 = wid * 512;
    const int lo1 = 2048 + wid * 512;

    const int swk = (((l >> 4) ^ (rl & 3))) * 8;

    gload_lds16(Ag0,      sA[0] + lo0);
    gload_lds16(Ag1,      sA[0] + lo1);
    gload_lds16(Bg0,      sB[0] + lo0);
    gload_lds16(Bg1,      sB[0] + lo1);
    gload_lds16(Ag0 + 32, sA[1] + lo0);
    gload_lds16(Ag1 + 32, sA[1] + lo1);
    gload_lds16(Bg0 + 32, sB[1] + lo0);
    gload_lds16(Bg1 + 32, sB[1] + lo1);

    f16 *curA = sA[0], *nxtA = sA[1], *farA = sA[2];
    f16 *curB = sB[0], *nxtB = sB[1], *farB = sB[2];

    for (int kt = 0; kt < nk; ++kt) {
        asm volatile("s_waitcnt vmcnt(4)" ::: "memory");
        __builtin_amdgcn_s_barrier();
        asm volatile("" ::: "memory");

        const int ktn = (kt + 2 < nk) ? kt + 2 : nk - 1;
        const int kof = ktn * 32;
        gload_lds16(Ag0 + kof, farA + lo0);
        gload_lds16(Ag1 + kof, farA + lo1);
        gload_lds16(Bg0 + kof, farB + lo0);
        gload_lds16(Bg1 + kof, farB + lo1);

        f16x8 a[4], b[4];
        #pragma unroll
        for (int f = 0; f < 4; ++f) {
            a[f] = *(const f16x8*)&curA[(wm + f * 16 + rl) * 32 + swk];
            b[f] = *(const f16x8*)&curB[(wn + f * 16 + rl) * 32 + swk];
        }
        // swapped: acc reg walks N
        #pragma unroll
        for (int fm = 0; fm < 4; ++fm)
            #pragma unroll
            for (int fn = 0; fn < 4; ++fn)
                acc[fm][fn] = __builtin_amdgcn_mfma_f32_16x16x32_f16(
                    b[fn], a[fm], acc[fm][fn], 0, 0, 0);

        f16* tA = curA; curA = nxtA; nxtA = farA; farA = tA;
        f16* tB = curB; curB = nxtB; nxtB = farB; farB = tB;
    }
    asm volatile("s_waitcnt vmcnt(0)" ::: "memory");

    const int rh = l >> 4;
    f16* outHz = outH + (size_t)z * batchC;
    #pragma unroll
    for (int fm = 0; fm < 4; ++fm) {
        const int row = m0 + wm + fm * 16 + rl;
        #pragma unroll
        for (int fn = 0; fn < 4; ++fn) {
            const int colb = n0 + wn + fn * 16 + rh * 4;
            f16x4 o;
            #pragma unroll
            for (int r = 0; r < 4; ++r) o[r] = (f16)acc[fm][fn][r];
            *(f16x4*)(outHz + (size_t)row * N + colb) = o;
        }
    }
}

extern "C" void kernel_launch(void* const* d_in, const int* in_sizes, int n_in,
                              void* d_out, int out_size, void* d_ws, size_t ws_size,
                              hipStream_t stream) {
    const float* x     = (const float*)d_in[0];
    const float* gamma = (const float*)d_in[1];
    const float* beta  = (const float*)d_in[2];
    const float* w1    = (const float*)d_in[3];
    const float* b1    = (const float*)d_in[4];
    const float* w2    = (const float*)d_in[5];
    const float* b2    = (const float*)d_in[6];
    float* out = (float*)d_out;

    const int BS = 4, T = 2048, DIM = 1024, HID = 2048;
    const int M = BS * T;  // 8192
    const long long MB = 1024 * 1024;

    // workspace layout (112 MiB total)
    char* ws = (char*)d_ws;
    f16*   x_h   = (f16*)(ws + 0 * MB);    // 16 MiB [M][DIM]
    f16*   y_h   = (f16*)(ws + 16 * MB);   // 16 MiB [M][DIM]
    f16*   h     = (f16*)(ws + 32 * MB);   // 32 MiB [M][HID]
    f16*   pre_h = h;                      // alias: f16 [M][DIM] (16MB), h dead after g1
    f16*   y2t   = (f16*)(ws + 64 * MB);   // 16 MiB [BS][DIM][T]
    f16*   x_t   = (f16*)(ws + 80 * MB);   // 16 MiB [BS][DIM][T]
    f16*   G     = (f16*)(ws + 96 * MB);   // 8 MiB  [BS][DIM][DIM]
    f16*   w1t   = (f16*)(ws + 104 * MB);  // 4 MiB  [HID][DIM]
    f16*   w2t   = (f16*)(ws + 108 * MB);  // 4 MiB  [DIM][HID]

    // 1) first LN + fp16 casts
    ln_cast_kernel<<<M, 256, 0, stream>>>(x, gamma, beta, y_h, x_h);

    // 2) weight transposes to fp16 [N][K]
    transpose_cast_kernel<<<dim3(HID / 32, DIM / 32), 256, 0, stream>>>(w1, w1t, DIM, HID);
    transpose_cast_kernel<<<dim3(DIM / 32, HID / 32), 256, 0, stream>>>(w2, w2t, HID, DIM);

    // 3) h = gelu(y @ w1 + b1)   [M][HID]  -- 256x128 phased ring-3, swapped epi
    gemm256x128_nt_kernel<0><<<dim3(M / 256, HID / 128, 1), 512, 0, stream>>>(
        y_h, w1t, b1, nullptr, h, M, HID, DIM, 0, 0, 0);

    // 4) y2t[z][f][t] = (h @ w2 + b2)[z*T+t][f]  -- LDS-transpose epilogue
    gemm256x128_nt_kernel<1><<<dim3(M / 256, DIM / 128, 1), 512, 0, stream>>>(
        h, w2t, b2, nullptr, y2t, M, DIM, HID, 0, 0, 0);

    // 5) x_t[z][f][t] = x_h[z*T+t][f]
    transpose_f16_kernel<<<dim3(DIM / 32, T / 32, BS), 256, 0, stream>>>(x_h, x_t, T, DIM);

    // 6) G'[z][f2][f1] = sum_t y2t[z][f2][t] * x_t[z][f1][t]  -- 128^2 ring-3
    gemm_nt_kernel<<<dim3(DIM / 128, DIM / 128, BS), 256, 0, stream>>>(
        y2t, x_t, G, DIM, DIM, T,
        (long long)DIM * T, (long long)DIM * T, (long long)DIM * DIM);

    // 7) pre_h[z][t][f] = sum_k x_h[z][t][k] * G'[z][f][k] + x  (f16 out)
    gemm256x128_nt_kernel<3><<<dim3(T / 256, DIM / 128, BS), 512, 0, stream>>>(
        x_h, G, nullptr, x, pre_h, T, DIM, DIM,
        (long long)T * DIM, (long long)DIM * DIM, (long long)T * DIM);

    // 8) final LN (f16 input)
    ln_final_kernel<<<M, 256, 0, stream>>>(pre_h, gamma, beta, out);
}

// Round 11
// 182.258 us; speedup vs baseline: 1.2719x; 1.0845x over previous
//
#include <hip/hip_runtime.h>
#include <hip/hip_fp16.h>

typedef _Float16 f16;
typedef _Float16 f16x8 __attribute__((ext_vector_type(8)));
typedef _Float16 f16x4 __attribute__((ext_vector_type(4)));
typedef float f32x4 __attribute__((ext_vector_type(4)));

#define LN_EPS 1e-5f

// erf via Abramowitz-Stegun 7.1.26 (|eps| <= 1.5e-7)
__device__ __forceinline__ float erf_fast(float x) {
    const float ax = __builtin_fabsf(x);
    const float t = 1.0f / (1.0f + 0.3275911f * ax);
    const float y = t * (0.254829592f +
                    t * (-0.284496736f +
                    t * (1.421413741f +
                    t * (-1.453152027f +
                    t * 1.061405429f))));
    const float r = 1.0f - y * __expf(-ax * ax);
    return __builtin_copysignf(r, x);
}

__device__ __forceinline__ float gelu_exact(float v) {
    return 0.5f * v * (1.0f + erf_fast(v * 0.70710678118654752440f));
}

// async global -> LDS, 16B per lane; lds dest is wave-uniform base (+lane*16 by HW)
__device__ __forceinline__ void gload_lds16(const f16* g, f16* l) {
    __builtin_amdgcn_global_load_lds(
        (const __attribute__((address_space(1))) unsigned int*)(g),
        (__attribute__((address_space(3))) unsigned int*)(l),
        16, 0, 0);
}

// ---------------- LayerNorm(x) -> y_h (fp16), plus x -> x_h (fp16) ----------
__global__ __launch_bounds__(256)
void ln_cast_kernel(const float* __restrict__ x,
                    const float* __restrict__ gamma,
                    const float* __restrict__ beta,
                    f16* __restrict__ y_h,
                    f16* __restrict__ x_h) {
    const int row = blockIdx.x;
    const int t = threadIdx.x;
    const size_t base = (size_t)row * 1024;
    float4 v = ((const float4*)(x + base))[t];
    float s  = v.x + v.y + v.z + v.w;
    float s2 = v.x*v.x + v.y*v.y + v.z*v.z + v.w*v.w;
    #pragma unroll
    for (int off = 32; off > 0; off >>= 1) {
        s  += __shfl_down(s, off, 64);
        s2 += __shfl_down(s2, off, 64);
    }
    __shared__ float ls[4], ls2[4];
    const int wid = t >> 6;
    if ((t & 63) == 0) { ls[wid] = s; ls2[wid] = s2; }
    __syncthreads();
    if (t == 0) {
        ls[0]  = ls[0] + ls[1] + ls[2] + ls[3];
        ls2[0] = ls2[0] + ls2[1] + ls2[2] + ls2[3];
    }
    __syncthreads();
    const float mu   = ls[0] * (1.0f / 1024.0f);
    const float var  = ls2[0] * (1.0f / 1024.0f) - mu * mu;
    const float rstd = rsqrtf(var + LN_EPS);
    const float4 g  = ((const float4*)gamma)[t];
    const float4 bt = ((const float4*)beta)[t];
    f16x4 yo, xo;
    yo[0] = (f16)((v.x - mu) * rstd * g.x + bt.x);
    yo[1] = (f16)((v.y - mu) * rstd * g.y + bt.y);
    yo[2] = (f16)((v.z - mu) * rstd * g.z + bt.z);
    yo[3] = (f16)((v.w - mu) * rstd * g.w + bt.w);
    xo[0] = (f16)v.x; xo[1] = (f16)v.y; xo[2] = (f16)v.z; xo[3] = (f16)v.w;
    *(f16x4*)(y_h + base + t * 4) = yo;
    *(f16x4*)(x_h + base + t * 4) = xo;
}

// ---------------- final LayerNorm: pre (f16) -> out (fp32) ----------------
__global__ __launch_bounds__(256)
void ln_final_kernel(const f16* __restrict__ pre,
                     const float* __restrict__ gamma,
                     const float* __restrict__ beta,
                     float* __restrict__ out) {
    const int row = blockIdx.x;
    const int t = threadIdx.x;
    const size_t base = (size_t)row * 1024;
    const f16x4 vh = *(const f16x4*)(pre + base + t * 4);
    float4 v;
    v.x = (float)vh[0]; v.y = (float)vh[1]; v.z = (float)vh[2]; v.w = (float)vh[3];
    float s  = v.x + v.y + v.z + v.w;
    float s2 = v.x*v.x + v.y*v.y + v.z*v.z + v.w*v.w;
    #pragma unroll
    for (int off = 32; off > 0; off >>= 1) {
        s  += __shfl_down(s, off, 64);
        s2 += __shfl_down(s2, off, 64);
    }
    __shared__ float ls[4], ls2[4];
    const int wid = t >> 6;
    if ((t & 63) == 0) { ls[wid] = s; ls2[wid] = s2; }
    __syncthreads();
    if (t == 0) {
        ls[0]  = ls[0] + ls[1] + ls[2] + ls[3];
        ls2[0] = ls2[0] + ls2[1] + ls2[2] + ls2[3];
    }
    __syncthreads();
    const float mu   = ls[0] * (1.0f / 1024.0f);
    const float var  = ls2[0] * (1.0f / 1024.0f) - mu * mu;
    const float rstd = rsqrtf(var + LN_EPS);
    const float4 g  = ((const float4*)gamma)[t];
    const float4 bt = ((const float4*)beta)[t];
    float4 o;
    o.x = (v.x - mu) * rstd * g.x + bt.x;
    o.y = (v.y - mu) * rstd * g.y + bt.y;
    o.z = (v.z - mu) * rstd * g.z + bt.z;
    o.w = (v.w - mu) * rstd * g.w + bt.w;
    ((float4*)(out + base))[t] = o;
}

// ------- merged weight transposes: fp32 [R,C] -> fp16 [C,R] for w1,w2 ------
__global__ __launch_bounds__(256)
void wt_transpose_kernel(const float* __restrict__ w1, const float* __restrict__ w2,
                         f16* __restrict__ w1t, f16* __restrict__ w2t) {
    __shared__ float tile[32][33];
    int bid = blockIdx.x;
    const float* src; f16* dst; int R, C, cx, ry;
    if (bid < 2048) {            // w1: [1024][2048] -> w1t [2048][1024]
        src = w1; dst = w1t; R = 1024; C = 2048; cx = bid & 63; ry = bid >> 6;
    } else {                     // w2: [2048][1024] -> w2t [1024][2048]
        bid -= 2048;
        src = w2; dst = w2t; R = 2048; C = 1024; cx = bid & 31; ry = bid >> 5;
    }
    const int c0 = cx * 32, r0 = ry * 32;
    const int tx = threadIdx.x & 31, ty = threadIdx.x >> 5;
    #pragma unroll
    for (int i = 0; i < 4; ++i) {
        const int r = ty + i * 8;
        tile[r][tx] = src[(size_t)(r0 + r) * C + c0 + tx];
    }
    __syncthreads();
    #pragma unroll
    for (int i = 0; i < 4; ++i) {
        const int r = ty + i * 8;
        dst[(size_t)(c0 + r) * R + r0 + tx] = (f16)tile[tx][r];
    }
}

// ------------- batched transpose fp16 [R,C] -> fp16 [C,R] ------------------
__global__ __launch_bounds__(256)
void transpose_f16_kernel(const f16* __restrict__ src,
                          f16* __restrict__ dst, int R, int C) {
    __shared__ f16 tile[32][33];
    const size_t zb = (size_t)blockIdx.z * R * C;
    src += zb; dst += zb;
    const int c0 = blockIdx.x * 32, r0 = blockIdx.y * 32;
    const int tx = threadIdx.x & 31, ty = threadIdx.x >> 5;
    #pragma unroll
    for (int i = 0; i < 4; ++i) {
        const int r = ty + i * 8;
        tile[r][tx] = src[(size_t)(r0 + r) * C + c0 + tx];
    }
    __syncthreads();
    #pragma unroll
    for (int i = 0; i < 4; ++i) {
        const int r = ty + i * 8;
        dst[(size_t)(c0 + r) * R + r0 + tx] = tile[tx][r];
    }
}

// ---------------- Gpair[2b] += Gpair[2b+1]  (split-K fold, in place) -------
__global__ __launch_bounds__(256)
void gsum_kernel(f16* __restrict__ g) {
    const size_t per = (size_t)1024 * 1024;
    f16* a = g + (size_t)blockIdx.y * 2 * per
               + (size_t)blockIdx.x * 2048 + (size_t)threadIdx.x * 8;
    const f16* b = a + per;
    f16x8 va = *(f16x8*)a;
    const f16x8 vb = *(const f16x8*)b;
    #pragma unroll
    for (int i = 0; i < 8; ++i) va[i] = (f16)((float)va[i] + (float)vb[i]);
    *(f16x8*)a = va;
}

// ====== 256x128 8-wave GEMM (NT), BK=64, ring-3 LDS, 4 phases/K-tile =======
// (round-7/10 core, now with ldA/ldB: row stride may differ from K for
// split-K slices of y2t/x_t.)
// Wave grid 4(M) x 2(N), wave tile 64x64. LDS: A 3x32KB + B 3x16KB = 144KB.
// Per tile: vmcnt(6) -> barrier; phases stage kt+2 into slot(kt-1) and
// interleave ds_read/MFMA with lgkmcnt(0)+setprio per phase.
// Swizzle: 16B slot s of row r holds k-slot s^(r&7); pre-swizzled global src.
// EPI: 0 = +bias, gelu, f16 out [M][N]                 (swapped mfma(b,a))
//      1 = +bias, f16 out transposed per batch via LDS  (unswapped)
//      2 = plain f16 out, batched z=batch*2+khalf split-K (swapped)
//      3 = + xadd(fp32), f16 out [M][N] batched          (swapped)
template <int EPI>
__global__ __launch_bounds__(512, 2)
void gemm256x128_nt_kernel(const f16* __restrict__ A, const f16* __restrict__ Bt,
                           const float* __restrict__ bias,
                           const float* __restrict__ xadd,
                           f16* __restrict__ outH,
                           int M, int N, int K, int ldA, int ldB,
                           long long batchA, long long batchB, long long batchC) {
    __shared__ __attribute__((aligned(16))) f16 sA[3][256 * 64];
    __shared__ __attribute__((aligned(16))) f16 sB[3][128 * 64];

    const int z = blockIdx.z;
    if (EPI == 2) {
        // z = batch*2 + khalf; k-slice offset along the row (t-dim)
        A  += (size_t)(z >> 1) * batchA + (size_t)(z & 1) * 1024;
        Bt += (size_t)(z >> 1) * batchB + (size_t)(z & 1) * 1024;
    } else {
        A  += (size_t)z * batchA;
        Bt += (size_t)z * batchB;
    }

    const int m0 = blockIdx.x * 256;
    const int n0 = blockIdx.y * 128;
    const int t = threadIdx.x;
    const int l = t & 63;
    const int wid = t >> 6;
    const int wr = wid >> 1;      // 0-3 (M)
    const int wc = wid & 1;       // 0-1 (N)
    const int rl = l & 15;
    const int g  = l >> 4;        // 0-3
    const int nk = K >> 6;

    const int rowS = t >> 3;                       // 0..63
    const int kbS  = ((t & 7) ^ (rowS & 7)) * 8;
    const f16* pA = A  + (size_t)(m0 + rowS) * ldA + kbS;
    const f16* pB = Bt + (size_t)(n0 + rowS) * ldB + kbS;
    const int ldsS = wid * 512;

    const int rA = wr * 64 + rl;
    const int rB = wc * 64 + rl;
    const int swk0 = ((g)     ^ (rl & 7)) * 8;
    const int swk1 = ((4 + g) ^ (rl & 7)) * 8;

    f32x4 acc[4][4] = {};

    auto mf = [&](f32x4 c, f16x8 af, f16x8 bf) {
        if constexpr (EPI != 1)
            return __builtin_amdgcn_mfma_f32_16x16x32_f16(bf, af, c, 0, 0, 0);
        else
            return __builtin_amdgcn_mfma_f32_16x16x32_f16(af, bf, c, 0, 0, 0);
    };

    auto stgA = [&](f16* dst, int u, int kc) {   // u = 0..3
        gload_lds16(pA + (size_t)u * 64 * ldA + kc * 64, dst + u * 4096 + ldsS);
    };
    auto stgB = [&](f16* dst, int u, int kc) {   // u = 0..1
        gload_lds16(pB + (size_t)u * 64 * ldB + kc * 64, dst + u * 4096 + ldsS);
    };

    // prologue: tiles 0 and 1 (12 units outstanding)
    const int t1 = (nk > 1) ? 1 : 0;
    #pragma unroll
    for (int u = 0; u < 4; ++u) stgA(sA[0], u, 0);
    #pragma unroll
    for (int u = 0; u < 2; ++u) stgB(sB[0], u, 0);
    #pragma unroll
    for (int u = 0; u < 4; ++u) stgA(sA[1], u, t1);
    #pragma unroll
    for (int u = 0; u < 2; ++u) stgB(sB[1], u, t1);

    f16 *curA = sA[0], *nxtA = sA[1], *farA = sA[2];
    f16 *curB = sB[0], *nxtB = sB[1], *farB = sB[2];

    f16x8 a[4][2], b[4][2];

    for (int kt = 0; kt < nk; ++kt) {
        asm volatile("s_waitcnt vmcnt(6)" ::: "memory");
        __builtin_amdgcn_s_barrier();

        const int kt2 = (kt + 2 < nk) ? kt + 2 : nk - 1;

        // P0: rd a01+b01, stg A-units 0,1; MFMA fm01 x fn01
        #pragma unroll
        for (int fm = 0; fm < 2; ++fm) {
            a[fm][0] = *(const f16x8*)(curA + (rA + fm * 16) * 64 + swk0);
            a[fm][1] = *(const f16x8*)(curA + (rA + fm * 16) * 64 + swk1);
        }
        #pragma unroll
        for (int fn = 0; fn < 2; ++fn) {
            b[fn][0] = *(const f16x8*)(curB + (rB + fn * 16) * 64 + swk0);
            b[fn][1] = *(const f16x8*)(curB + (rB + fn * 16) * 64 + swk1);
        }
        stgA(farA, 0, kt2);
        stgA(farA, 1, kt2);
        asm volatile("s_waitcnt lgkmcnt(0)" ::: "memory");
        __builtin_amdgcn_sched_barrier(0);
        __builtin_amdgcn_s_setprio(1);
        #pragma unroll
        for (int fm = 0; fm < 2; ++fm)
            #pragma unroll
            for (int fn = 0; fn < 2; ++fn) {
                acc[fm][fn] = mf(acc[fm][fn], a[fm][0], b[fn][0]);
                acc[fm][fn] = mf(acc[fm][fn], a[fm][1], b[fn][1]);
            }
        __builtin_amdgcn_s_setprio(0);

        // P1: rd b23, stg A-units 2,3; MFMA fm01 x fn23
        #pragma unroll
        for (int fn = 2; fn < 4; ++fn) {
            b[fn][0] = *(const f16x8*)(curB + (rB + fn * 16) * 64 + swk0);
            b[fn][1] = *(const f16x8*)(curB + (rB + fn * 16) * 64 + swk1);
        }
        stgA(farA, 2, kt2);
        stgA(farA, 3, kt2);
        asm volatile("s_waitcnt lgkmcnt(0)" ::: "memory");
        __builtin_amdgcn_sched_barrier(0);
        __builtin_amdgcn_s_setprio(1);
        #pragma unroll
        for (int fm = 0; fm < 2; ++fm)
            #pragma unroll
            for (int fn = 2; fn < 4; ++fn) {
                acc[fm][fn] = mf(acc[fm][fn], a[fm][0], b[fn][0]);
                acc[fm][fn] = mf(acc[fm][fn], a[fm][1], b[fn][1]);
            }
        __builtin_amdgcn_s_setprio(0);

        // P2: rd a23, stg B-units 0,1; MFMA fm23 x fn23
        #pragma unroll
        for (int fm = 2; fm < 4; ++fm) {
            a[fm][0] = *(const f16x8*)(curA + (rA + fm * 16) * 64 + swk0);
            a[fm][1] = *(const f16x8*)(curA + (rA + fm * 16) * 64 + swk1);
        }
        stgB(farB, 0, kt2);
        stgB(farB, 1, kt2);
        asm volatile("s_waitcnt lgkmcnt(0)" ::: "memory");
        __builtin_amdgcn_sched_barrier(0);
        __builtin_amdgcn_s_setprio(1);
        #pragma unroll
        for (int fm = 2; fm < 4; ++fm)
            #pragma unroll
            for (int fn = 2; fn < 4; ++fn) {
                acc[fm][fn] = mf(acc[fm][fn], a[fm][0], b[fn][0]);
                acc[fm][fn] = mf(acc[fm][fn], a[fm][1], b[fn][1]);
            }
        __builtin_amdgcn_s_setprio(0);

        // P3: MFMA fm23 x fn01 (operands in regs)
        __builtin_amdgcn_s_setprio(1);
        #pragma unroll
        for (int fm = 2; fm < 4; ++fm)
            #pragma unroll
            for (int fn = 0; fn < 2; ++fn) {
                acc[fm][fn] = mf(acc[fm][fn], a[fm][0], b[fn][0]);
                acc[fm][fn] = mf(acc[fm][fn], a[fm][1], b[fn][1]);
            }
        __builtin_amdgcn_s_setprio(0);

        f16* tp;
        tp = curA; curA = nxtA; nxtA = farA; farA = tp;
        tp = curB; curB = nxtB; nxtB = farB; farB = tp;
    }

    // ---------------- epilogue ----------------
    if (EPI == 1) {
        // LDS-transpose epilogue: coalesced writes to y2t (round-10 win).
        __syncthreads();
        f16* lds_t = (f16*)sA;
        #pragma unroll
        for (int fm = 0; fm < 4; ++fm) {
            const int rowb = wr * 64 + fm * 16 + g * 4;
            #pragma unroll
            for (int fn = 0; fn < 4; ++fn) {
                const int cl = wc * 64 + fn * 16 + rl;
                const float bv = bias[n0 + cl];
                f16x4 o;
                #pragma unroll
                for (int r = 0; r < 4; ++r) o[r] = (f16)(acc[fm][fn][r] + bv);
                *(f16x4*)&lds_t[cl * 264 + rowb] = o;
            }
        }
        __syncthreads();
        const int lh = l & 31, ch = l >> 5;
        #pragma unroll
        for (int it = 0; it < 8; ++it) {
            const int c = it * 16 + wid * 2 + ch;
            const f16x8 vv = *(const f16x8*)&lds_t[c * 264 + lh * 8];
            const int rowg = m0 + lh * 8;
            const int zz = rowg >> 11, rr = rowg & 2047;
            *(f16x8*)(outH + ((size_t)zz * N + (n0 + c)) * 2048 + rr) = vv;
        }
    } else {
        asm volatile("s_waitcnt vmcnt(0)" ::: "memory");
        // swapped: lane rl walks M-row, reg r walks N-col -> vector stores
        const float* xaddz = xadd;
        f16* outHz = outH;
        if (EPI == 3 || EPI == 2) {
            outHz += (size_t)z * batchC;
            if (EPI == 3) xaddz += (size_t)z * batchC;
        }
        #pragma unroll
        for (int fm = 0; fm < 4; ++fm) {
            const int row = m0 + wr * 64 + fm * 16 + rl;
            #pragma unroll
            for (int fn = 0; fn < 4; ++fn) {
                const int colb = n0 + wc * 64 + fn * 16 + g * 4;
                if (EPI == 0) {
                    const float4 bv = *(const float4*)&bias[colb];
                    f16x4 o;
                    o[0] = (f16)gelu_exact(acc[fm][fn][0] + bv.x);
                    o[1] = (f16)gelu_exact(acc[fm][fn][1] + bv.y);
                    o[2] = (f16)gelu_exact(acc[fm][fn][2] + bv.z);
                    o[3] = (f16)gelu_exact(acc[fm][fn][3] + bv.w);
                    *(f16x4*)(outH + (size_t)row * N + colb) = o;
                } else if (EPI == 2) {
                    f16x4 o;
                    #pragma unroll
                    for (int r = 0; r < 4; ++r) o[r] = (f16)acc[fm][fn][r];
                    *(f16x4*)(outHz + (size_t)row * N + colb) = o;
                } else {
                    const size_t idx = (size_t)row * N + colb;
                    const float4 xa = *(const float4*)&xaddz[idx];
                    f16x4 o;
                    o[0] = (f16)(acc[fm][fn][0] + xa.x);
                    o[1] = (f16)(acc[fm][fn][1] + xa.y);
                    o[2] = (f16)(acc[fm][fn][2] + xa.z);
                    o[3] = (f16)(acc[fm][fn][3] + xa.w);
                    *(f16x4*)(outHz + idx) = o;
                }
            }
        }
    }
}

extern "C" void kernel_launch(void* const* d_in, const int* in_sizes, int n_in,
                              void* d_out, int out_size, void* d_ws, size_t ws_size,
                              hipStream_t stream) {
    const float* x     = (const float*)d_in[0];
    const float* gamma = (const float*)d_in[1];
    const float* beta  = (const float*)d_in[2];
    const float* w1    = (const float*)d_in[3];
    const float* b1    = (const float*)d_in[4];
    const float* w2    = (const float*)d_in[5];
    const float* b2    = (const float*)d_in[6];
    float* out = (float*)d_out;

    const int BS = 4, T = 2048, DIM = 1024, HID = 2048;
    const int M = BS * T;  // 8192
    const long long MB = 1024 * 1024;

    // workspace layout (120 MiB total; round-1 footprint, known-good)
    char* ws = (char*)d_ws;
    f16*   x_h   = (f16*)(ws + 0 * MB);    // 16 MiB [M][DIM]
    f16*   y_h   = (f16*)(ws + 16 * MB);   // 16 MiB [M][DIM]
    f16*   h     = (f16*)(ws + 32 * MB);   // 32 MiB [M][HID]
    f16*   pre_h = h;                      // alias: f16 [M][DIM], h dead after g1
    f16*   y2t   = (f16*)(ws + 64 * MB);   // 16 MiB [BS][DIM][T]
    f16*   x_t   = (f16*)(ws + 80 * MB);   // 16 MiB [BS][DIM][T]
    f16*   Gpair = (f16*)(ws + 96 * MB);   // 16 MiB [8][1024][1024] (split-K pairs)
    f16*   w1t   = (f16*)(ws + 112 * MB);  // 4 MiB  [HID][DIM]
    f16*   w2t   = (f16*)(ws + 116 * MB);  // 4 MiB  [DIM][HID]

    // 1) first LN + fp16 casts
    ln_cast_kernel<<<M, 256, 0, stream>>>(x, gamma, beta, y_h, x_h);

    // 2) both weight transposes, one dispatch
    wt_transpose_kernel<<<4096, 256, 0, stream>>>(w1, w2, w1t, w2t);

    // 3) h = gelu(y @ w1 + b1)   [M][HID]
    gemm256x128_nt_kernel<0><<<dim3(M / 256, HID / 128, 1), 512, 0, stream>>>(
        y_h, w1t, b1, nullptr, h, M, HID, DIM, DIM, DIM, 0, 0, 0);

    // 4) y2t[z][f][t] = (h @ w2 + b2)[z*T+t][f]  -- LDS-transpose epilogue
    gemm256x128_nt_kernel<1><<<dim3(M / 256, DIM / 128, 1), 512, 0, stream>>>(
        h, w2t, b2, nullptr, y2t, M, DIM, HID, HID, HID, 0, 0, 0);

    // 5) x_t[z][f][t] = x_h[z*T+t][f]
    transpose_f16_kernel<<<dim3(DIM / 32, T / 32, BS), 256, 0, stream>>>(x_h, x_t, T, DIM);

    // 6) Gpair[b*2+kh][f2][f1] = sum_{t in half kh} y2t[b][f2][t]*x_t[b][f1][t]
    //    split-K=2: grid z=8 -> 256 blocks = 1/CU at 8 waves (was 1 wave/SIMD)
    gemm256x128_nt_kernel<2><<<dim3(DIM / 256, DIM / 128, BS * 2), 512, 0, stream>>>(
        y2t, x_t, nullptr, nullptr, Gpair, DIM, DIM, T / 2, T, T,
        (long long)DIM * T, (long long)DIM * T, (long long)DIM * DIM);

    // 7) fold halves: Gpair[2b] += Gpair[2b+1]
    gsum_kernel<<<dim3(512, BS), 256, 0, stream>>>(Gpair);

    // 8) pre_h[z][t][f] = sum_k x_h[z][t][k] * Gpair[2z][f][k] + x  (f16 out)
    gemm256x128_nt_kernel<3><<<dim3(T / 256, DIM / 128, BS), 512, 0, stream>>>(
        x_h, Gpair, nullptr, x, pre_h, T, DIM, DIM, DIM, DIM,
        (long long)T * DIM, (long long)2 * DIM * DIM, (long long)T * DIM);

    // 9) final LN (f16 input)
    ln_final_kernel<<<M, 256, 0, stream>>>(pre_h, gamma, beta, out);
}